// Round 6
// baseline (271.136 us; speedup 1.0000x reference)
//
#include <hip/hip_runtime.h>
#include <hip/hip_bf16.h>
#include <math.h>

// OptimizeSNR via MFMA: out[n, t+m] = sum_p A[m,p] * B[p,n]
//   A[m,p] = k[p-m]  (16x160 kernel Toeplitz, 5 frags/filter, in VGPRs)
//   B[p,n] = x_rowN[s0+p]  (bf16 in LDS, 16 rows per block)
// R6: small blocks for TLP — 256 thr, MLEN=512, single 21 KB LDS buffer,
//     7 blocks/CU; normal (L2-merged) stores. No explicit pipeline.
constexpr int Bc = 8, Cc = 128, Lc = 32768, Kc = 129, PAD = Kc / 2;

constexpr int ROWS   = 16;            // channel-rows per block (MFMA N dim)
constexpr int MLEN   = 512;           // output positions per block per row
constexpr int PSPAN  = MLEN + 144;    // staged positions incl. halo = 656
constexpr int PSTR   = 664;           // padded row stride (2B*PSTR % 16 == 0)
constexpr int THREADS= 256;
constexpr int NTILES = MLEN / 16;     // 32
constexpr int NWAVES = THREADS / 64;  // 4
constexpr int TPW    = NTILES / NWAVES; // 8
constexpr int NQ     = PSPAN / 4;     // 164 float4 quads per row
constexpr int NF     = 11;            // load iterations (16 thr/row)

typedef __attribute__((ext_vector_type(8))) short short8;
typedef __attribute__((ext_vector_type(4))) float floatx4;

__device__ __forceinline__ unsigned short f2bf(float f) {
    return __builtin_bit_cast(unsigned short, __float2bfloat16(f));
}

// Per-channel complex scale: sc = nm*cos(atan(a)), ss = nm*sin(atan(a))
__global__ void scale_kernel(const float* __restrict__ wm,
                             const float* __restrict__ wa,
                             float* __restrict__ ws, int C, float batchf) {
    int c = threadIdx.x;
    if (c >= C) return;
    float m = -1e30f;
    for (int i = 0; i < C; ++i) m = fmaxf(m, wm[i]);
    float s = 0.f;
    for (int i = 0; i < C; ++i) s += expf(wm[i] - m);
    float nm = batchf * expf(wm[c] - m) / s;
    float a = wa[c];
    float inv = rsqrtf(1.f + a * a);
    ws[2 * c]     = nm * inv;       // sc
    ws[2 * c + 1] = nm * a * inv;   // ss
}

__global__ __launch_bounds__(THREADS, 7)
void mf_kernel(const float* __restrict__ x,
               const float* __restrict__ kr,
               const float* __restrict__ ki,
               const float* __restrict__ sc_ss,
               float* __restrict__ out, int interleaved) {
    __shared__ __align__(16) unsigned short lx[ROWS * PSTR];

    const int bx   = blockIdx.x;       // position tile
    const int bg   = blockIdx.y;       // row group (16 rows)
    const int row0 = bg * ROWS;
    const int P0   = bx * MLEN;
    const int s0   = P0 - PAD;

    const int tid  = threadIdx.x;
    const int lane = tid & 63;
    const int fh   = lane >> 4;        // 0..3
    const int fn   = lane & 15;        // 0..15
    const int wv   = tid >> 6;         // wave 0..3

    // ---- A fragments: A_d[m][kl] = k[32d + kl - m]; lane holds m=fn, kl=8*fh+e ----
    short8 ar[5], ai[5];
    #pragma unroll
    for (int d = 0; d < 5; ++d) {
        #pragma unroll
        for (int e = 0; e < 8; ++e) {
            int idx = 32 * d + 8 * fh + e - fn;
            bool ok = (idx >= 0) && (idx < Kc);
            ar[d][e] = (short)f2bf(ok ? kr[idx] : 0.f);
            ai[d][e] = (short)f2bf(ok ? ki[idx] : 0.f);
        }
    }

    // ---- stage x[row0..row0+15][s0 .. s0+PSPAN) as bf16 into LDS ----
    const int srow = tid >> 4;         // 16 threads per row
    const int scol = tid & 15;
    const float* __restrict__ xr = x + (size_t)(row0 + srow) * Lc;
    unsigned short* lrow = &lx[srow * PSTR];
    const bool interior = (s0 >= 0) && (s0 + PSPAN <= Lc);
    #pragma unroll
    for (int i = 0; i < NF; ++i) {
        const int i4 = scol + 16 * i;
        if (i4 < NQ) {
            const int g = s0 + 4 * i4;
            float4 v;
            if (interior) {
                v = *reinterpret_cast<const float4*>(xr + g);
            } else {
                v.x = (g + 0 >= 0 && g + 0 < Lc) ? xr[g + 0] : 0.f;
                v.y = (g + 1 >= 0 && g + 1 < Lc) ? xr[g + 1] : 0.f;
                v.z = (g + 2 >= 0 && g + 2 < Lc) ? xr[g + 2] : 0.f;
                v.w = (g + 3 >= 0 && g + 3 < Lc) ? xr[g + 3] : 0.f;
            }
            __hip_bfloat162 p0 = __float22bfloat162_rn(make_float2(v.x, v.y));
            __hip_bfloat162 p1 = __float22bfloat162_rn(make_float2(v.z, v.w));
            ushort2 u0, u1;
            __builtin_memcpy(&u0, &p0, 4);
            __builtin_memcpy(&u1, &p1, 4);
            ushort4 h;
            h.x = u0.x; h.y = u0.y; h.z = u1.x; h.w = u1.y;
            *reinterpret_cast<ushort4*>(&lrow[4 * i4]) = h;
        }
    }
    __syncthreads();

    // ---- per-lane channel scale (lane owns channel-row row0+fn) ----
    const int ch = (row0 + fn) & (Cc - 1);
    const float scv = sc_ss[2 * ch];
    const float ssv = sc_ss[2 * ch + 1];

    #pragma unroll
    for (int jj = 0; jj < TPW; ++jj) {
        const int j  = wv * TPW + jj;
        const int pb = 16 * j;
        // B frag: lane holds B[kl=8*fh+e][n=fn] = x_row(fn)[s0 + pb + 32d + 8*fh + e]
        const unsigned short* lp = &lx[fn * PSTR + pb + 8 * fh];
        floatx4 cr = {0.f, 0.f, 0.f, 0.f};
        floatx4 cim = {0.f, 0.f, 0.f, 0.f};
        #pragma unroll
        for (int d = 0; d < 5; ++d) {
            short8 b = *reinterpret_cast<const short8*>(lp + 32 * d);
            cr  = __builtin_amdgcn_mfma_f32_16x16x32_bf16(ar[d], b, cr, 0, 0, 0);
            cim = __builtin_amdgcn_mfma_f32_16x16x32_bf16(ai[d], b, cim, 0, 0, 0);
        }
        // D layout: lane holds D[m = 4*fh + r][n = fn]
        const size_t obase = (size_t)(row0 + fn) * Lc + P0 + pb + 4 * fh;
        if (!interleaved) {
            float4 o;
            o.x = scv * cr[0] - ssv * cim[0];
            o.y = scv * cr[1] - ssv * cim[1];
            o.z = scv * cr[2] - ssv * cim[2];
            o.w = scv * cr[3] - ssv * cim[3];
            *reinterpret_cast<float4*>(out + obase) = o;
        } else {
            float2* o2 = reinterpret_cast<float2*>(out) + obase;
            #pragma unroll
            for (int r = 0; r < 4; ++r) {
                o2[r] = make_float2(scv * cr[r] - ssv * cim[r],
                                    -scv * cim[r] - ssv * cr[r]);
            }
        }
    }
}

extern "C" void kernel_launch(void* const* d_in, const int* in_sizes, int n_in,
                              void* d_out, int out_size, void* d_ws, size_t ws_size,
                              hipStream_t stream) {
    const float* x  = (const float*)d_in[0];
    const float* wm = (const float*)d_in[1];
    const float* wa = (const float*)d_in[2];
    const float* kr = (const float*)d_in[3];
    const float* ki = (const float*)d_in[4];
    float* out = (float*)d_out;
    float* ws  = (float*)d_ws;

    const int C = in_sizes[1];  // 128
    const long long N = (long long)Bc * Cc * Lc;
    const int interleaved = (out_size == 2 * N) ? 1 : 0;

    hipLaunchKernelGGL(scale_kernel, dim3(1), dim3(C), 0, stream,
                       wm, wa, ws, C, (float)Bc);

    dim3 grid(Lc / MLEN, (Bc * Cc) / ROWS);   // 64 x 64 = 4096 blocks
    hipLaunchKernelGGL(mf_kernel, grid, dim3(THREADS), 0, stream,
                       x, kr, ki, ws, out, interleaved);
}

// Round 7
// 78.766 us; speedup vs baseline: 3.4423x; 3.4423x over previous
//
#include <hip/hip_runtime.h>
#include <hip/hip_bf16.h>
#include <math.h>

// OptimizeSNR via MFMA: out[n, t+m] = sum_p A[m,p] * B[p,n]
//   A[m,p] = k[p-m]  (16x160 kernel Toeplitz, 5 frags/filter, in VGPRs)
//   B[p,n] = x_rowN[s0+p]  (bf16 in LDS, 16 rows per block)
// R7 = R3 tiling (MLEN=1024, ROWS=16, 37.8 KB LDS, 2048 blocks) with
//      256-thread workgroups: same traffic shape, more co-resident WGs/CU
//      so staging of one block overlaps compute of another.
constexpr int Bc = 8, Cc = 128, Lc = 32768, Kc = 129, PAD = Kc / 2;

constexpr int ROWS   = 16;            // channel-rows per block (MFMA N dim)
constexpr int MLEN   = 1024;          // output positions per block per row
constexpr int PSPAN  = MLEN + 144;    // staged positions incl. halo = 1168
constexpr int PSTR   = 1176;          // padded row stride (2B*PSTR % 16 == 0)
constexpr int THREADS= 256;
constexpr int NTILES = MLEN / 16;     // 64
constexpr int NWAVES = THREADS / 64;  // 4
constexpr int TPW    = NTILES / NWAVES; // 16 tiles per wave
constexpr int NQ     = PSPAN / 4;     // 292 float4 quads per row
constexpr int NF     = 19;            // staging iterations (16 thr/row)

typedef __attribute__((ext_vector_type(8))) short short8;
typedef __attribute__((ext_vector_type(4))) float floatx4;

__device__ __forceinline__ unsigned short f2bf(float f) {
    return __builtin_bit_cast(unsigned short, __float2bfloat16(f));
}

// Per-channel complex scale: sc = nm*cos(atan(a)), ss = nm*sin(atan(a))
__global__ void scale_kernel(const float* __restrict__ wm,
                             const float* __restrict__ wa,
                             float* __restrict__ ws, int C, float batchf) {
    int c = threadIdx.x;
    if (c >= C) return;
    float m = -1e30f;
    for (int i = 0; i < C; ++i) m = fmaxf(m, wm[i]);
    float s = 0.f;
    for (int i = 0; i < C; ++i) s += expf(wm[i] - m);
    float nm = batchf * expf(wm[c] - m) / s;
    float a = wa[c];
    float inv = rsqrtf(1.f + a * a);
    ws[2 * c]     = nm * inv;       // sc
    ws[2 * c + 1] = nm * a * inv;   // ss
}

__global__ __launch_bounds__(THREADS, 4)
void mf_kernel(const float* __restrict__ x,
               const float* __restrict__ kr,
               const float* __restrict__ ki,
               const float* __restrict__ sc_ss,
               float* __restrict__ out, int interleaved) {
    __shared__ __align__(16) unsigned short lx[ROWS * PSTR];

    const int bx   = blockIdx.x;       // position tile
    const int bg   = blockIdx.y;       // row group (16 rows)
    const int row0 = bg * ROWS;
    const int P0   = bx * MLEN;
    const int s0   = P0 - PAD;

    const int tid  = threadIdx.x;
    const int lane = tid & 63;
    const int fh   = lane >> 4;        // 0..3
    const int fn   = lane & 15;        // 0..15
    const int wv   = tid >> 6;         // wave 0..3

    // ---- A fragments: A_d[m][kl] = k[32d + kl - m]; lane holds m=fn, kl=8*fh+e ----
    short8 ar[5], ai[5];
    #pragma unroll
    for (int d = 0; d < 5; ++d) {
        #pragma unroll
        for (int e = 0; e < 8; ++e) {
            int idx = 32 * d + 8 * fh + e - fn;
            bool ok = (idx >= 0) && (idx < Kc);
            ar[d][e] = (short)f2bf(ok ? kr[idx] : 0.f);
            ai[d][e] = (short)f2bf(ok ? ki[idx] : 0.f);
        }
    }

    // ---- stage x[row0..row0+15][s0 .. s0+PSPAN) as bf16 into LDS ----
    const int srow = tid >> 4;         // 16 threads per row
    const int scol = tid & 15;
    const float* __restrict__ xr = x + (size_t)(row0 + srow) * Lc;
    unsigned short* lrow = &lx[srow * PSTR];
    const bool interior = (s0 >= 0) && (s0 + PSPAN <= Lc);
    #pragma unroll
    for (int i = 0; i < NF; ++i) {
        const int i4 = scol + 16 * i;
        if (i4 < NQ) {
            const int g = s0 + 4 * i4;
            float4 v;
            if (interior) {
                v = *reinterpret_cast<const float4*>(xr + g);
            } else {
                v.x = (g + 0 >= 0 && g + 0 < Lc) ? xr[g + 0] : 0.f;
                v.y = (g + 1 >= 0 && g + 1 < Lc) ? xr[g + 1] : 0.f;
                v.z = (g + 2 >= 0 && g + 2 < Lc) ? xr[g + 2] : 0.f;
                v.w = (g + 3 >= 0 && g + 3 < Lc) ? xr[g + 3] : 0.f;
            }
            __hip_bfloat162 p0 = __float22bfloat162_rn(make_float2(v.x, v.y));
            __hip_bfloat162 p1 = __float22bfloat162_rn(make_float2(v.z, v.w));
            ushort2 u0, u1;
            __builtin_memcpy(&u0, &p0, 4);
            __builtin_memcpy(&u1, &p1, 4);
            ushort4 h;
            h.x = u0.x; h.y = u0.y; h.z = u1.x; h.w = u1.y;
            *reinterpret_cast<ushort4*>(&lrow[4 * i4]) = h;
        }
    }
    __syncthreads();

    // ---- per-lane channel scale (lane owns channel-row row0+fn) ----
    const int ch = (row0 + fn) & (Cc - 1);
    const float scv = sc_ss[2 * ch];
    const float ssv = sc_ss[2 * ch + 1];

    #pragma unroll
    for (int jj = 0; jj < TPW; ++jj) {
        const int j  = wv * TPW + jj;
        const int pb = 16 * j;
        // B frag: lane holds B[kl=8*fh+e][n=fn] = x_row(fn)[s0 + pb + 32d + 8*fh + e]
        const unsigned short* lp = &lx[fn * PSTR + pb + 8 * fh];
        floatx4 cr = {0.f, 0.f, 0.f, 0.f};
        floatx4 cim = {0.f, 0.f, 0.f, 0.f};
        #pragma unroll
        for (int d = 0; d < 5; ++d) {
            short8 b = *reinterpret_cast<const short8*>(lp + 32 * d);
            cr  = __builtin_amdgcn_mfma_f32_16x16x32_bf16(ar[d], b, cr, 0, 0, 0);
            cim = __builtin_amdgcn_mfma_f32_16x16x32_bf16(ai[d], b, cim, 0, 0, 0);
        }
        // D layout: lane holds D[m = 4*fh + r][n = fn]
        const size_t obase = (size_t)(row0 + fn) * Lc + P0 + pb + 4 * fh;
        if (!interleaved) {
            float4 o;
            o.x = scv * cr[0] - ssv * cim[0];
            o.y = scv * cr[1] - ssv * cim[1];
            o.z = scv * cr[2] - ssv * cim[2];
            o.w = scv * cr[3] - ssv * cim[3];
            *reinterpret_cast<float4*>(out + obase) = o;
        } else {
            float2* o2 = reinterpret_cast<float2*>(out) + obase;
            #pragma unroll
            for (int r = 0; r < 4; ++r) {
                o2[r] = make_float2(scv * cr[r] - ssv * cim[r],
                                    -scv * cim[r] - ssv * cr[r]);
            }
        }
    }
}

extern "C" void kernel_launch(void* const* d_in, const int* in_sizes, int n_in,
                              void* d_out, int out_size, void* d_ws, size_t ws_size,
                              hipStream_t stream) {
    const float* x  = (const float*)d_in[0];
    const float* wm = (const float*)d_in[1];
    const float* wa = (const float*)d_in[2];
    const float* kr = (const float*)d_in[3];
    const float* ki = (const float*)d_in[4];
    float* out = (float*)d_out;
    float* ws  = (float*)d_ws;

    const int C = in_sizes[1];  // 128
    const long long N = (long long)Bc * Cc * Lc;
    const int interleaved = (out_size == 2 * N) ? 1 : 0;

    hipLaunchKernelGGL(scale_kernel, dim3(1), dim3(C), 0, stream,
                       wm, wa, ws, C, (float)Bc);

    dim3 grid(Lc / MLEN, (Bc * Cc) / ROWS);   // 32 x 64 = 2048 blocks
    hipLaunchKernelGGL(mf_kernel, grid, dim3(THREADS), 0, stream,
                       x, kr, ki, ws, out, interleaved);
}